// Round 4
// baseline (615.668 us; speedup 1.0000x reference)
//
#include <hip/hip_runtime.h>
#include <math.h>

typedef unsigned short u16;
typedef __bf16 bf16_t;
typedef u16 u16x4 __attribute__((ext_vector_type(4)));
typedef u16 u16x8 __attribute__((ext_vector_type(8)));
typedef bf16_t bf16x8 __attribute__((ext_vector_type(8)));
typedef float f32x4 __attribute__((ext_vector_type(4)));

__device__ __forceinline__ float bf2f(u16 v) {
    union { unsigned u; float f; } x; x.u = ((unsigned)v) << 16; return x.f;
}
// Native f32->bf16 (RNE) scalar cast: compiler emits the hw convert.
__device__ __forceinline__ u16 f2bf(float f) {
    union { bf16_t b; u16 u; } x; x.b = (bf16_t)f; return x.u;
}

// ---------------------------------------------------------------------------
// Runtime dtype detector (probe = Wq). bf16: high byte of each u32 is sign/exp
// in [0x38,0x3F]; fp32: uniform mantissa byte. 64-lane majority => exact.
// ---------------------------------------------------------------------------
__device__ __forceinline__ bool is_bf16_input(const unsigned* __restrict__ probe) {
    unsigned w = probe[(threadIdx.x & 63) * 32771 + 7];
    unsigned b7 = (w >> 8) & 0x7f;
    bool hit = (b7 >= 0x38) && (b7 <= 0x3f);
    return __builtin_popcountll(__ballot(hit)) >= 32;
}

__global__ __launch_bounds__(256) void convert_kernel(
    const void* __restrict__ src, u16* __restrict__ dst, int n,
    const unsigned* __restrict__ probe)
{
    bool bf = is_bf16_input(probe);
    int i = (blockIdx.x * 256 + threadIdx.x) * 8;
    if (i >= n) return;
    if (bf) {
        *(u16x8*)&dst[i] = *(const u16x8*)&((const u16*)src)[i];
    } else {
        const float* s = (const float*)src + i;
        u16x8 o;
#pragma unroll
        for (int j = 0; j < 8; j++) o[j] = f2bf(s[j]);
        *(u16x8*)&dst[i] = o;
    }
}

__global__ __launch_bounds__(256) void tconv_kernel(
    const void* __restrict__ in, u16* __restrict__ out, int R, int C,
    const unsigned* __restrict__ probe)
{
    bool bf = is_bf16_input(probe);
    __shared__ u16 t[32][33];
    int x = threadIdx.x & 31, y = threadIdx.x >> 5;
    int bx = blockIdx.x * 32, by = blockIdx.y * 32;
    if (bf) {
        const u16* s = (const u16*)in;
#pragma unroll
        for (int i = 0; i < 32; i += 8)
            t[y + i][x] = s[(size_t)(by + y + i) * C + bx + x];
    } else {
        const float* s = (const float*)in;
#pragma unroll
        for (int i = 0; i < 32; i += 8)
            t[y + i][x] = f2bf(s[(size_t)(by + y + i) * C + bx + x]);
    }
    __syncthreads();
#pragma unroll
    for (int i = 0; i < 32; i += 8)
        out[(size_t)(bx + y + i) * R + by + x] = t[x][y + i];
}

__global__ __launch_bounds__(256) void transpose_kernel(
    const u16* __restrict__ in, u16* __restrict__ out, int R, int C)
{
    __shared__ u16 t[32][33];
    int x = threadIdx.x & 31, y = threadIdx.x >> 5;
    int bx = blockIdx.x * 32, by = blockIdx.y * 32;
#pragma unroll
    for (int i = 0; i < 32; i += 8)
        t[y + i][x] = in[(size_t)(by + y + i) * C + bx + x];
    __syncthreads();
#pragma unroll
    for (int i = 0; i < 32; i += 8)
        out[(size_t)(bx + y + i) * R + by + x] = t[x][y + i];
}

// ---------------------------------------------------------------------------
// GEMM: C[M,N] = (A[M,K] @ BT[N,K]^T + bias[N]) * scale
// ---------------------------------------------------------------------------
#define GSTR 40

__global__ __launch_bounds__(256) void gemm_bias_kernel(
    const u16* __restrict__ A, const u16* __restrict__ BT,
    const u16* __restrict__ bias, void* __restrict__ Cout,
    int M, int N, int K, const unsigned* __restrict__ probe, float scale)
{
    __shared__ __align__(16) u16 As[128 * GSTR];
    __shared__ __align__(16) u16 Bs[128 * GSTR];
    const int tid  = threadIdx.x;
    const int lane = tid & 63, wave = tid >> 6;
    const int quad = lane >> 4, li = lane & 15;
    const int bm = blockIdx.x * 128, bn = blockIdx.y * 128;
    const int wm = (wave >> 1) * 64, wn = (wave & 1) * 64;
    const int srow = tid >> 2;
    const int scol = (tid & 3) * 8;

    f32x4 acc[4][4] = {};

    for (int k0 = 0; k0 < K; k0 += 32) {
#pragma unroll
        for (int p = 0; p < 2; p++) {
            int r = srow + p * 64;
            u16x8 av = *(const u16x8*)&A [(size_t)(bm + r) * K + k0 + scol];
            u16x8 bv = *(const u16x8*)&BT[(size_t)(bn + r) * K + k0 + scol];
            *(u16x8*)&As[r * GSTR + scol] = av;
            *(u16x8*)&Bs[r * GSTR + scol] = bv;
        }
        __syncthreads();
        bf16x8 af[4], bfr[4];
#pragma unroll
        for (int i = 0; i < 4; i++)
            af[i]  = *(const bf16x8*)&As[(wm + i * 16 + li) * GSTR + quad * 8];
#pragma unroll
        for (int i = 0; i < 4; i++)
            bfr[i] = *(const bf16x8*)&Bs[(wn + i * 16 + li) * GSTR + quad * 8];
#pragma unroll
        for (int mt = 0; mt < 4; mt++)
#pragma unroll
            for (int nt = 0; nt < 4; nt++)
                acc[mt][nt] = __builtin_amdgcn_mfma_f32_16x16x32_bf16(
                    af[mt], bfr[nt], acc[mt][nt], 0, 0, 0);
        __syncthreads();
    }

    bool bf = probe ? is_bf16_input(probe) : true;
    if (bf) {
        u16* C16 = (u16*)Cout;
#pragma unroll
        for (int nt = 0; nt < 4; nt++) {
            int col = bn + wn + nt * 16 + li;
            float bb = bf2f(bias[col]);
#pragma unroll
            for (int mt = 0; mt < 4; mt++)
#pragma unroll
                for (int r = 0; r < 4; r++) {
                    int row = bm + wm + mt * 16 + quad * 4 + r;
                    C16[(size_t)row * N + col] = f2bf((acc[mt][nt][r] + bb) * scale);
                }
        }
    } else {
        float* Cf = (float*)Cout;
#pragma unroll
        for (int nt = 0; nt < 4; nt++) {
            int col = bn + wn + nt * 16 + li;
            float bb = bf2f(bias[col]);
#pragma unroll
            for (int mt = 0; mt < 4; mt++)
#pragma unroll
                for (int r = 0; r < 4; r++) {
                    int row = bm + wm + mt * 16 + quad * 4 + r;
                    Cf[(size_t)row * N + col] = (acc[mt][nt][r] + bb) * scale;
                }
        }
    }
}

// ---------------------------------------------------------------------------
// Flash attention v7 (causal GQA). v3 inner body (straight-line softmax,
// per-tile mask, KVBLK=32) with a restructured schedule:
//   - QBLK=64: 2-wave blocks (128 thr), grid (32,16,2)=1024 blocks -> finer
//     granularity, ~4 blocks/CU avg (v3/v6 were grid-capped at 2/CU and
//     wall-time = critical path of heavy diagonal blocks).
//   - heavy-first dispatch (qt = 31 - blockIdx.x): LPT scheduling; the 32
//     heaviest blocks start first, light blocks pack the tail.
//   - double-buffered K/V LDS, ONE barrier per iteration: issue next-tile
//     global loads at iter top -> barrier -> compute buf[p] -> ds_write
//     buf[p^1] (loads land during compute; next barrier publishes writes).
//     v3 paid 2 barriers + a write-before-read commit stall (~4900cy/iter).
//   - exp2 softmax: Q pre-scaled by log2(e)/sqrt(dh) in the Q-GEMM epilogue.
// Bank conflicts measured negligible (5.9M cy vs 119G total) -> padded
// layouts kept, no swizzle.
// Q:[B*S, D] (pre-scaled)  K:[B*S, KV]  VT:[KV, B*S]  O:[B*S, D].
// Grid (S/64, H, B), 128 threads.
// ---------------------------------------------------------------------------
__global__ __launch_bounds__(128) void flash_kernel(
    const u16* __restrict__ Q, const u16* __restrict__ Kg,
    const u16* __restrict__ VT, u16* __restrict__ O)
{
    constexpr int S = 2048, D = 2048, DH = 128, KVC = 512;
    __shared__ __align__(16) u16 Ks[2][32 * 136];  // [buf][key][dh]   17408 B
    __shared__ __align__(16) u16 Vt[2][128 * 40];  // [buf][dh][key]   20480 B
    __shared__ __align__(16) u16 Pw[2][32 * 40];   // [wave][qrow][key] 5120 B

    const int tid  = threadIdx.x;
    const int wave = tid >> 6, lane = tid & 63;
    const int quad = lane >> 4, li = lane & 15;
    const int qt = 31 - (int)blockIdx.x;           // heavy blocks first
    const int h = blockIdx.y, b = blockIdx.z;
    const int g = h >> 2;
    const int q0w = qt * 64 + wave * 32;           // this wave's first q-row

    const u16* Qb = Q  + (size_t)b * S * D;
    const u16* Kb = Kg + (size_t)b * S * KVC;
    const u16* Vg = VT + (size_t)g * DH * (2 * S) + (size_t)b * S;

    // Q fragments: B-operand, rows q0w + m*16 + li, k = quad*8 (+c*32)
    bf16x8 qf[2][4];
#pragma unroll
    for (int m = 0; m < 2; m++)
#pragma unroll
        for (int c = 0; c < 4; c++)
            qf[m][c] = *(const bf16x8*)&Qb[(size_t)(q0w + m * 16 + li) * D
                                           + h * DH + c * 32 + quad * 8];

    f32x4 oacc[2][8] = {};
    float mr[2] = { -INFINITY, -INFINITY };
    float lr[2] = { 0.f, 0.f };

    const int kend = qt * 64 + 64;

    // --- register prefetch of tile kc=0 and commit to buf 0 ---
    u16x8 kreg[4], vreg[4];
#pragma unroll
    for (int ch = 0; ch < 4; ch++) {
        int idx = tid + ch * 128;
        kreg[ch] = *(const u16x8*)&Kb[(size_t)(idx >> 4) * KVC + g * DH + (idx & 15) * 8];
        vreg[ch] = *(const u16x8*)&Vg[(size_t)(idx >> 2) * (2 * S) + (idx & 3) * 8];
    }
#pragma unroll
    for (int ch = 0; ch < 4; ch++) {
        int idx = tid + ch * 128;
        *(u16x8*)&Ks[0][(idx >> 4) * 136 + (idx & 15) * 8] = kreg[ch];
        *(u16x8*)&Vt[0][(idx >> 2) * 40  + (idx & 3) * 8]  = vreg[ch];
    }

    int pb = 0;
    for (int kc = 0; kc < kend; kc += 32) {
        const int kn = kc + 32;
        const bool have_next = (kn < kend);

        // issue next-tile global loads (land during compute below)
        if (have_next) {
#pragma unroll
            for (int ch = 0; ch < 4; ch++) {
                int idx = tid + ch * 128;
                kreg[ch] = *(const u16x8*)&Kb[(size_t)(kn + (idx >> 4)) * KVC
                                              + g * DH + (idx & 15) * 8];
                vreg[ch] = *(const u16x8*)&Vg[(size_t)(idx >> 2) * (2 * S)
                                              + kn + (idx & 3) * 8];
            }
        }

        // publishes last iter's ds_writes of buf[pb]; all waves done reading buf[pb^1]
        __syncthreads();

        if (kc <= q0w) {   // causal: tiles fully above the diagonal are skipped
            // S^T = K · Q^T : sacc[m][t], C row = key (quad*4+r), col = qrow (li)
            f32x4 sacc[2][2] = {};
#pragma unroll
            for (int t = 0; t < 2; t++)
#pragma unroll
                for (int c = 0; c < 4; c++) {
                    bf16x8 kf = *(const bf16x8*)&Ks[pb][(t * 16 + li) * 136 + c * 32 + quad * 8];
#pragma unroll
                    for (int m = 0; m < 2; m++)
                        sacc[m][t] = __builtin_amdgcn_mfma_f32_16x16x32_bf16(
                            kf, qf[m][c], sacc[m][t], 0, 0, 0);
                }

            float alpha_b[2][4];
#pragma unroll
            for (int m = 0; m < 2; m++) {
                int row = q0w + m * 16 + li;
                f32x4 s0 = sacc[m][0];
                f32x4 s1 = sacc[m][1];
#pragma unroll
                for (int r = 0; r < 4; r++) {
                    int k0 = kc + quad * 4 + r;
                    if (k0 > row)      s0[r] = -INFINITY;
                    if (k0 + 16 > row) s1[r] = -INFINITY;
                }
                float mx = fmaxf(fmaxf(fmaxf(s0[0], s0[1]), fmaxf(s0[2], s0[3])),
                                 fmaxf(fmaxf(s1[0], s1[1]), fmaxf(s1[2], s1[3])));
                mx = fmaxf(mx, __shfl_xor(mx, 16));
                mx = fmaxf(mx, __shfl_xor(mx, 32));
                float mnew = fmaxf(mr[m], mx);
                float al = exp2f(mr[m] - mnew);
                mr[m] = mnew;
                f32x4 p0, p1;
                float ps = 0.f;
#pragma unroll
                for (int r = 0; r < 4; r++) {
                    p0[r] = exp2f(s0[r] - mnew);
                    p1[r] = exp2f(s1[r] - mnew);
                    ps += p0[r] + p1[r];
                }
                ps += __shfl_xor(ps, 16);
                ps += __shfl_xor(ps, 32);
                lr[m] = lr[m] * al + ps;
                u16x4 c0, c1;
#pragma unroll
                for (int r = 0; r < 4; r++) { c0[r] = f2bf(p0[r]); c1[r] = f2bf(p1[r]); }
                *(u16x4*)&Pw[wave][(m * 16 + li) * 40 + quad * 4]      = c0;
                *(u16x4*)&Pw[wave][(m * 16 + li) * 40 + 16 + quad * 4] = c1;
#pragma unroll
                for (int r = 0; r < 4; r++)
                    alpha_b[m][r] = __shfl(al, quad * 4 + r, 16);
            }

            // rescale O accumulators
#pragma unroll
            for (int m = 0; m < 2; m++)
#pragma unroll
                for (int dt = 0; dt < 8; dt++)
#pragma unroll
                    for (int r = 0; r < 4; r++)
                        oacc[m][dt][r] *= alpha_b[m][r];

            // drain P stores (same wave) before vector re-read
            asm volatile("s_waitcnt lgkmcnt(0)" ::: "memory");
            union { u16x8 u; bf16x8 bv; } pc0, pc1;
            pc0.u = *(const u16x8*)&Pw[wave][(0 * 16 + li) * 40 + quad * 8];
            pc1.u = *(const u16x8*)&Pw[wave][(1 * 16 + li) * 40 + quad * 8];
            bf16x8 pf[2] = { pc0.bv, pc1.bv };

            // O += P · V
#pragma unroll
            for (int dt = 0; dt < 8; dt++) {
                bf16x8 vf = *(const bf16x8*)&Vt[pb][(dt * 16 + li) * 40 + quad * 8];
#pragma unroll
                for (int m = 0; m < 2; m++)
                    oacc[m][dt] = __builtin_amdgcn_mfma_f32_16x16x32_bf16(
                        pf[m], vf, oacc[m][dt], 0, 0, 0);
            }
        }

        // commit next tile into the other buffer (published by next barrier)
        if (have_next) {
#pragma unroll
            for (int ch = 0; ch < 4; ch++) {
                int idx = tid + ch * 128;
                *(u16x8*)&Ks[pb ^ 1][(idx >> 4) * 136 + (idx & 15) * 8] = kreg[ch];
                *(u16x8*)&Vt[pb ^ 1][(idx >> 2) * 40  + (idx & 3) * 8]  = vreg[ch];
            }
        }
        pb ^= 1;
    }

    u16* Ob = O + (size_t)b * S * D;
#pragma unroll
    for (int m = 0; m < 2; m++) {
#pragma unroll
        for (int r = 0; r < 4; r++) {
            float linv = 1.0f / __shfl(lr[m], quad * 4 + r, 16);
            int row = q0w + m * 16 + quad * 4 + r;
#pragma unroll
            for (int dt = 0; dt < 8; dt++)
                Ob[(size_t)row * D + h * DH + dt * 16 + li] = f2bf(oacc[m][dt][r] * linv);
        }
    }
}

// ---------------------------------------------------------------------------
extern "C" void kernel_launch(void* const* d_in, const int* in_sizes, int n_in,
                              void* d_out, int out_size, void* d_ws, size_t ws_size,
                              hipStream_t stream)
{
    const void* X  = d_in[0];
    const void* Wq = d_in[3];
    const void* bq = d_in[4];
    const void* Wk = d_in[5];
    const void* bk = d_in[6];
    const void* Wv = d_in[7];
    const void* bv = d_in[8];
    const void* Wo = d_in[9];
    const void* bo = d_in[10];
    const unsigned* probe = (const unsigned*)d_in[3];

    u16* ws  = (u16*)d_ws;
    u16* Xc  = ws;                   // [4096][2048]
    u16* WT  = Xc  + 8388608;        // [2048][2048] WqT, later WoT
    u16* WkT = WT  + 4194304;        // [512][2048]
    u16* WvT = WkT + 1048576;        // [512][2048]
    u16* bqc = WvT + 1048576;        // 2048
    u16* bkc = bqc + 2048;           // 512
    u16* bvc = bkc + 512;            // 512
    u16* boc = bvc + 512;            // 2048
    u16* Qb  = boc + 2048;           // [4096][2048]
    u16* Kb  = Qb  + 8388608;        // [4096][512]
    u16* Vb  = Kb  + 2097152;        // [4096][512]
    u16* VTb = Vb  + 2097152;        // [512][4096]
    u16* Ob  = VTb + 2097152;        // [4096][2048]

    convert_kernel<<<4096, 256, 0, stream>>>(X,  Xc,  8388608, probe);
    convert_kernel<<<1,    256, 0, stream>>>(bq, bqc, 2048, probe);
    convert_kernel<<<1,    256, 0, stream>>>(bk, bkc, 512,  probe);
    convert_kernel<<<1,    256, 0, stream>>>(bv, bvc, 512,  probe);
    convert_kernel<<<1,    256, 0, stream>>>(bo, boc, 2048, probe);

    tconv_kernel<<<dim3(16, 64), 256, 0, stream>>>(Wk, WkT, 2048, 512, probe);
    tconv_kernel<<<dim3(16, 64), 256, 0, stream>>>(Wv, WvT, 2048, 512, probe);
    tconv_kernel<<<dim3(64, 64), 256, 0, stream>>>(Wq, WT,  2048, 2048, probe);

    // log2(e)/sqrt(DH) folded into Q projection: exp() becomes exp2()
    gemm_bias_kernel<<<dim3(32, 16), 256, 0, stream>>>(Xc, WT,  bqc, Qb, 4096, 2048, 2048, nullptr, 0.12751743482175434f);
    gemm_bias_kernel<<<dim3(32, 4),  256, 0, stream>>>(Xc, WkT, bkc, Kb, 4096, 512, 2048, nullptr, 1.0f);
    gemm_bias_kernel<<<dim3(32, 4),  256, 0, stream>>>(Xc, WvT, bvc, Vb, 4096, 512, 2048, nullptr, 1.0f);

    transpose_kernel<<<dim3(16, 128), 256, 0, stream>>>(Vb, VTb, 4096, 512);

    flash_kernel<<<dim3(32, 16, 2), 128, 0, stream>>>(Qb, Kb, VTb, Ob);

    tconv_kernel<<<dim3(64, 64), 256, 0, stream>>>(Wo, WT, 2048, 2048, probe);

    gemm_bias_kernel<<<dim3(32, 16), 256, 0, stream>>>(Ob, WT, boc, d_out, 4096, 2048, 2048, probe, 1.0f);
}

// Round 5
// 528.602 us; speedup vs baseline: 1.1647x; 1.1647x over previous
//
#include <hip/hip_runtime.h>
#include <math.h>

typedef unsigned short u16;
typedef __bf16 bf16_t;
typedef u16 u16x4 __attribute__((ext_vector_type(4)));
typedef u16 u16x8 __attribute__((ext_vector_type(8)));
typedef bf16_t bf16x8 __attribute__((ext_vector_type(8)));
typedef float f32x4 __attribute__((ext_vector_type(4)));

__device__ __forceinline__ float bf2f(u16 v) {
    union { unsigned u; float f; } x; x.u = ((unsigned)v) << 16; return x.f;
}
// Native f32->bf16 (RNE) scalar cast: compiler emits the hw convert.
__device__ __forceinline__ u16 f2bf(float f) {
    union { bf16_t b; u16 u; } x; x.b = (bf16_t)f; return x.u;
}

// Async global->LDS DMA, 16B per lane. LDS dest = wave-uniform base + lane*16
// (hardware-defined); global src is per-lane. Guide m97: +67% over reg-staging.
__device__ __forceinline__ void gload16(const u16* g, u16* l) {
    __builtin_amdgcn_global_load_lds(
        (const __attribute__((address_space(1))) void*)g,
        (__attribute__((address_space(3))) void*)l,
        16, 0, 0);
}

// ---------------------------------------------------------------------------
// Runtime dtype detector (probe = Wq). bf16: high byte of each u32 is sign/exp
// in [0x38,0x3F]; fp32: uniform mantissa byte. 64-lane majority => exact.
// ---------------------------------------------------------------------------
__device__ __forceinline__ bool is_bf16_input(const unsigned* __restrict__ probe) {
    unsigned w = probe[(threadIdx.x & 63) * 32771 + 7];
    unsigned b7 = (w >> 8) & 0x7f;
    bool hit = (b7 >= 0x38) && (b7 <= 0x3f);
    return __builtin_popcountll(__ballot(hit)) >= 32;
}

__global__ __launch_bounds__(256) void convert_kernel(
    const void* __restrict__ src, u16* __restrict__ dst, int n,
    const unsigned* __restrict__ probe)
{
    bool bf = is_bf16_input(probe);
    int i = (blockIdx.x * 256 + threadIdx.x) * 8;
    if (i >= n) return;
    if (bf) {
        *(u16x8*)&dst[i] = *(const u16x8*)&((const u16*)src)[i];
    } else {
        const float* s = (const float*)src + i;
        u16x8 o;
#pragma unroll
        for (int j = 0; j < 8; j++) o[j] = f2bf(s[j]);
        *(u16x8*)&dst[i] = o;
    }
}

__global__ __launch_bounds__(256) void tconv_kernel(
    const void* __restrict__ in, u16* __restrict__ out, int R, int C,
    const unsigned* __restrict__ probe)
{
    bool bf = is_bf16_input(probe);
    __shared__ u16 t[32][33];
    int x = threadIdx.x & 31, y = threadIdx.x >> 5;
    int bx = blockIdx.x * 32, by = blockIdx.y * 32;
    if (bf) {
        const u16* s = (const u16*)in;
#pragma unroll
        for (int i = 0; i < 32; i += 8)
            t[y + i][x] = s[(size_t)(by + y + i) * C + bx + x];
    } else {
        const float* s = (const float*)in;
#pragma unroll
        for (int i = 0; i < 32; i += 8)
            t[y + i][x] = f2bf(s[(size_t)(by + y + i) * C + bx + x]);
    }
    __syncthreads();
#pragma unroll
    for (int i = 0; i < 32; i += 8)
        out[(size_t)(bx + y + i) * R + by + x] = t[x][y + i];
}

__global__ __launch_bounds__(256) void transpose_kernel(
    const u16* __restrict__ in, u16* __restrict__ out, int R, int C)
{
    __shared__ u16 t[32][33];
    int x = threadIdx.x & 31, y = threadIdx.x >> 5;
    int bx = blockIdx.x * 32, by = blockIdx.y * 32;
#pragma unroll
    for (int i = 0; i < 32; i += 8)
        t[y + i][x] = in[(size_t)(by + y + i) * C + bx + x];
    __syncthreads();
#pragma unroll
    for (int i = 0; i < 32; i += 8)
        out[(size_t)(bx + y + i) * R + by + x] = t[x][y + i];
}

// ---------------------------------------------------------------------------
// GEMM: C[M,N] = (A[M,K] @ BT[N,K]^T + bias[N]) * scale
// m97 staging (guide §5 step 3): global_load_lds width=16 into LINEAR
// [128][32] LDS tiles (no pad -- DMA dest is wave-uniform base + lane*16).
// Per K-step: 4 async loads/thread, barrier (drains vmcnt), 8 ds_read_b128,
// 16 MFMA, barrier. Fragment reads at 64B row stride x quad*16B chunks hit
// all 8 128B slots per cycle group -- same geometry m97 ran at 874 TF.
// ---------------------------------------------------------------------------
__global__ __launch_bounds__(256) void gemm_bias_kernel(
    const u16* __restrict__ A, const u16* __restrict__ BT,
    const u16* __restrict__ bias, void* __restrict__ Cout,
    int M, int N, int K, const unsigned* __restrict__ probe, float scale)
{
    __shared__ __align__(16) u16 As[128 * 32];
    __shared__ __align__(16) u16 Bs[128 * 32];
    const int tid  = threadIdx.x;
    const int lane = tid & 63, wave = tid >> 6;
    const int quad = lane >> 4, li = lane & 15;
    const int bm = blockIdx.x * 128, bn = blockIdx.y * 128;
    const int wm = (wave >> 1) * 64, wn = (wave & 1) * 64;
    const int lrow = lane >> 2;          // 0..15 row within 16-row chunk
    const int lcol = (lane & 3) * 8;     // u16 col offset

    f32x4 acc[4][4] = {};

    for (int k0 = 0; k0 < K; k0 += 32) {
        // async-stage A and B tiles: chunk c = wave*2+j covers rows c*16..+15
#pragma unroll
        for (int j = 0; j < 2; j++) {
            int c = wave * 2 + j;
            int row = c * 16 + lrow;
            gload16(&A [(size_t)(bm + row) * K + k0 + lcol], &As[c * 16 * 32]);
            gload16(&BT[(size_t)(bn + row) * K + k0 + lcol], &Bs[c * 16 * 32]);
        }
        __syncthreads();   // compiler drains vmcnt(0) before barrier: tiles ready
        bf16x8 af[4], bfr[4];
#pragma unroll
        for (int i = 0; i < 4; i++)
            af[i]  = *(const bf16x8*)&As[(wm + i * 16 + li) * 32 + quad * 8];
#pragma unroll
        for (int i = 0; i < 4; i++)
            bfr[i] = *(const bf16x8*)&Bs[(wn + i * 16 + li) * 32 + quad * 8];
#pragma unroll
        for (int mt = 0; mt < 4; mt++)
#pragma unroll
            for (int nt = 0; nt < 4; nt++)
                acc[mt][nt] = __builtin_amdgcn_mfma_f32_16x16x32_bf16(
                    af[mt], bfr[nt], acc[mt][nt], 0, 0, 0);
        __syncthreads();
    }

    bool bf = probe ? is_bf16_input(probe) : true;
    if (bf) {
        u16* C16 = (u16*)Cout;
#pragma unroll
        for (int nt = 0; nt < 4; nt++) {
            int col = bn + wn + nt * 16 + li;
            float bb = bf2f(bias[col]);
#pragma unroll
            for (int mt = 0; mt < 4; mt++)
#pragma unroll
                for (int r = 0; r < 4; r++) {
                    int row = bm + wm + mt * 16 + quad * 4 + r;
                    C16[(size_t)row * N + col] = f2bf((acc[mt][nt][r] + bb) * scale);
                }
        }
    } else {
        float* Cf = (float*)Cout;
#pragma unroll
        for (int nt = 0; nt < 4; nt++) {
            int col = bn + wn + nt * 16 + li;
            float bb = bf2f(bias[col]);
#pragma unroll
            for (int mt = 0; mt < 4; mt++)
#pragma unroll
                for (int r = 0; r < 4; r++) {
                    int row = bm + wm + mt * 16 + quad * 4 + r;
                    Cf[(size_t)row * N + col] = (acc[mt][nt][r] + bb) * scale;
                }
        }
    }
}

// ---------------------------------------------------------------------------
// Flash attention v8 = v3 EXACTLY (the proven 165 µs structure: 4 waves/block,
// 128 q-rows, single-buffer K/V LDS staging + register prefetch, 2 barriers,
// straight-line softmax, per-tile mask). v4-v7 structural rewrites all
// regressed (241/206/194/250) -- v3 is the local optimum; do not perturb.
// Only two pure-VALU cuts that ran correctly in rounds 2-4:
//   - Q pre-scaled by log2(e)/sqrt(dh) in the Q-GEMM epilogue: the SCALE
//     multiply disappears and __expf becomes bare exp2f (v_exp_f32).
//   - native bf16 converts (f2bf helper).
// Q:[B*S, D] (pre-scaled)  K:[B*S, KV]  VT:[KV, B*S]  O:[B*S, D].
// Grid (S/128, H, B).
// ---------------------------------------------------------------------------
__global__ __launch_bounds__(256) void flash_kernel(
    const u16* __restrict__ Q, const u16* __restrict__ Kg,
    const u16* __restrict__ VT, u16* __restrict__ O)
{
    constexpr int S = 2048, D = 2048, DH = 128, KVC = 512;
    __shared__ __align__(16) u16 Ks[32 * 136];   // [key][dh]   8704 B
    __shared__ __align__(16) u16 Vt[128 * 40];   // [dh][key]  10240 B
    __shared__ __align__(16) u16 Pw[4][32 * 40]; // [qrow][key] 10240 B

    const int tid  = threadIdx.x;
    const int wave = tid >> 6, lane = tid & 63;
    const int quad = lane >> 4, li = lane & 15;
    const int qt = blockIdx.x, h = blockIdx.y, b = blockIdx.z;
    const int g = h >> 2;
    const int q0w = qt * 128 + wave * 32;        // this wave's first q-row

    const u16* Qb = Q  + (size_t)b * S * D;
    const u16* Kb = Kg + (size_t)b * S * KVC;
    const u16* Vg = VT + (size_t)g * DH * (2 * S) + (size_t)b * S;

    // Q fragments: B-operand, rows q0w + m*16 + li, k = quad*8 (+c*32)
    bf16x8 qf[2][4];
#pragma unroll
    for (int m = 0; m < 2; m++)
#pragma unroll
        for (int c = 0; c < 4; c++)
            qf[m][c] = *(const bf16x8*)&Qb[(size_t)(q0w + m * 16 + li) * D
                                           + h * DH + c * 32 + quad * 8];

    f32x4 oacc[2][8] = {};
    float mr[2] = { -INFINITY, -INFINITY };
    float lr[2] = { 0.f, 0.f };

    const int kend = qt * 128 + 128;

    // --- register prefetch of tile kc=0 ---
    u16x8 kreg[2], vreg[2];
#pragma unroll
    for (int ch = 0; ch < 2; ch++) {
        int idx = tid + ch * 256;
        kreg[ch] = *(const u16x8*)&Kb[(size_t)(idx >> 4) * KVC + g * DH + (idx & 15) * 8];
        vreg[ch] = *(const u16x8*)&Vg[(size_t)(idx >> 2) * (2 * S) + (idx & 3) * 8];
    }

    for (int kc = 0; kc < kend; kc += 32) {
        // commit prefetched tile to LDS
#pragma unroll
        for (int ch = 0; ch < 2; ch++) {
            int idx = tid + ch * 256;
            *(u16x8*)&Ks[(idx >> 4) * 136 + (idx & 15) * 8] = kreg[ch];
            *(u16x8*)&Vt[(idx >> 2) * 40  + (idx & 3) * 8]  = vreg[ch];
        }
        __syncthreads();

        // issue prefetch for next tile (overlaps with compute below)
        int kn = kc + 32;
        if (kn < kend) {
#pragma unroll
            for (int ch = 0; ch < 2; ch++) {
                int idx = tid + ch * 256;
                kreg[ch] = *(const u16x8*)&Kb[(size_t)(kn + (idx >> 4)) * KVC
                                              + g * DH + (idx & 15) * 8];
                vreg[ch] = *(const u16x8*)&Vg[(size_t)(idx >> 2) * (2 * S)
                                              + kn + (idx & 3) * 8];
            }
        }

        if (kc <= q0w) {   // causal: tiles with kc > q0w are fully masked
            // S^T = K · Q^T : sacc[m][t], C row = key (quad*4+r), col = qrow (li)
            f32x4 sacc[2][2] = {};
#pragma unroll
            for (int t = 0; t < 2; t++)
#pragma unroll
                for (int c = 0; c < 4; c++) {
                    bf16x8 kf = *(const bf16x8*)&Ks[(t * 16 + li) * 136 + c * 32 + quad * 8];
#pragma unroll
                    for (int m = 0; m < 2; m++)
                        sacc[m][t] = __builtin_amdgcn_mfma_f32_16x16x32_bf16(
                            kf, qf[m][c], sacc[m][t], 0, 0, 0);
                }

            float alpha_b[2][4];
#pragma unroll
            for (int m = 0; m < 2; m++) {
                int row = q0w + m * 16 + li;
                f32x4 s0 = sacc[m][0];
                f32x4 s1 = sacc[m][1];
#pragma unroll
                for (int r = 0; r < 4; r++) {
                    int k0 = kc + quad * 4 + r;
                    if (k0 > row)      s0[r] = -INFINITY;
                    if (k0 + 16 > row) s1[r] = -INFINITY;
                }
                float mx = fmaxf(fmaxf(fmaxf(s0[0], s0[1]), fmaxf(s0[2], s0[3])),
                                 fmaxf(fmaxf(s1[0], s1[1]), fmaxf(s1[2], s1[3])));
                mx = fmaxf(mx, __shfl_xor(mx, 16));
                mx = fmaxf(mx, __shfl_xor(mx, 32));
                float mnew = fmaxf(mr[m], mx);
                float al = exp2f(mr[m] - mnew);
                mr[m] = mnew;
                f32x4 p0, p1;
                float ps = 0.f;
#pragma unroll
                for (int r = 0; r < 4; r++) {
                    p0[r] = exp2f(s0[r] - mnew);
                    p1[r] = exp2f(s1[r] - mnew);
                    ps += p0[r] + p1[r];
                }
                ps += __shfl_xor(ps, 16);
                ps += __shfl_xor(ps, 32);
                lr[m] = lr[m] * al + ps;
                u16x4 c0, c1;
#pragma unroll
                for (int r = 0; r < 4; r++) { c0[r] = f2bf(p0[r]); c1[r] = f2bf(p1[r]); }
                *(u16x4*)&Pw[wave][(m * 16 + li) * 40 + quad * 4]      = c0;
                *(u16x4*)&Pw[wave][(m * 16 + li) * 40 + 16 + quad * 4] = c1;
#pragma unroll
                for (int r = 0; r < 4; r++)
                    alpha_b[m][r] = __shfl(al, quad * 4 + r, 16);
            }

            // rescale O accumulators
#pragma unroll
            for (int m = 0; m < 2; m++)
#pragma unroll
                for (int dt = 0; dt < 8; dt++)
#pragma unroll
                    for (int r = 0; r < 4; r++)
                        oacc[m][dt][r] *= alpha_b[m][r];

            // drain P stores (same wave) before vector re-read
            asm volatile("s_waitcnt lgkmcnt(0)" ::: "memory");
            union { u16x8 u; bf16x8 bv; } pc0, pc1;
            pc0.u = *(const u16x8*)&Pw[wave][(0 * 16 + li) * 40 + quad * 8];
            pc1.u = *(const u16x8*)&Pw[wave][(1 * 16 + li) * 40 + quad * 8];
            bf16x8 pf[2] = { pc0.bv, pc1.bv };

            // O += P · V
#pragma unroll
            for (int dt = 0; dt < 8; dt++) {
                bf16x8 vf = *(const bf16x8*)&Vt[(dt * 16 + li) * 40 + quad * 8];
#pragma unroll
                for (int m = 0; m < 2; m++)
                    oacc[m][dt] = __builtin_amdgcn_mfma_f32_16x16x32_bf16(
                        pf[m], vf, oacc[m][dt], 0, 0, 0);
            }
        }
        __syncthreads();
    }

    u16* Ob = O + (size_t)b * S * D;
#pragma unroll
    for (int m = 0; m < 2; m++) {
#pragma unroll
        for (int r = 0; r < 4; r++) {
            float linv = 1.0f / __shfl(lr[m], quad * 4 + r, 16);
            int row = q0w + m * 16 + quad * 4 + r;
#pragma unroll
            for (int dt = 0; dt < 8; dt++)
                Ob[(size_t)row * D + h * DH + dt * 16 + li] = f2bf(oacc[m][dt][r] * linv);
        }
    }
}

// ---------------------------------------------------------------------------
extern "C" void kernel_launch(void* const* d_in, const int* in_sizes, int n_in,
                              void* d_out, int out_size, void* d_ws, size_t ws_size,
                              hipStream_t stream)
{
    const void* X  = d_in[0];
    const void* Wq = d_in[3];
    const void* bq = d_in[4];
    const void* Wk = d_in[5];
    const void* bk = d_in[6];
    const void* Wv = d_in[7];
    const void* bv = d_in[8];
    const void* Wo = d_in[9];
    const void* bo = d_in[10];
    const unsigned* probe = (const unsigned*)d_in[3];

    u16* ws  = (u16*)d_ws;
    u16* Xc  = ws;                   // [4096][2048]
    u16* WT  = Xc  + 8388608;        // [2048][2048] WqT, later WoT
    u16* WkT = WT  + 4194304;        // [512][2048]
    u16* WvT = WkT + 1048576;        // [512][2048]
    u16* bqc = WvT + 1048576;        // 2048
    u16* bkc = bqc + 2048;           // 512
    u16* bvc = bkc + 512;            // 512
    u16* boc = bvc + 512;            // 2048
    u16* Qb  = boc + 2048;           // [4096][2048]
    u16* Kb  = Qb  + 8388608;        // [4096][512]
    u16* Vb  = Kb  + 2097152;        // [4096][512]
    u16* VTb = Vb  + 2097152;        // [512][4096]
    u16* Ob  = VTb + 2097152;        // [4096][2048]

    convert_kernel<<<4096, 256, 0, stream>>>(X,  Xc,  8388608, probe);
    convert_kernel<<<1,    256, 0, stream>>>(bq, bqc, 2048, probe);
    convert_kernel<<<1,    256, 0, stream>>>(bk, bkc, 512,  probe);
    convert_kernel<<<1,    256, 0, stream>>>(bv, bvc, 512,  probe);
    convert_kernel<<<1,    256, 0, stream>>>(bo, boc, 2048, probe);

    tconv_kernel<<<dim3(16, 64), 256, 0, stream>>>(Wk, WkT, 2048, 512, probe);
    tconv_kernel<<<dim3(16, 64), 256, 0, stream>>>(Wv, WvT, 2048, 512, probe);
    tconv_kernel<<<dim3(64, 64), 256, 0, stream>>>(Wq, WT,  2048, 2048, probe);

    // log2(e)/sqrt(DH) folded into Q projection: flash uses bare exp2
    gemm_bias_kernel<<<dim3(32, 16), 256, 0, stream>>>(Xc, WT,  bqc, Qb, 4096, 2048, 2048, nullptr, 0.12751743482175434f);
    gemm_bias_kernel<<<dim3(32, 4),  256, 0, stream>>>(Xc, WkT, bkc, Kb, 4096, 512, 2048, nullptr, 1.0f);
    gemm_bias_kernel<<<dim3(32, 4),  256, 0, stream>>>(Xc, WvT, bvc, Vb, 4096, 512, 2048, nullptr, 1.0f);

    transpose_kernel<<<dim3(16, 128), 256, 0, stream>>>(Vb, VTb, 4096, 512);

    flash_kernel<<<dim3(16, 16, 2), 256, 0, stream>>>(Qb, Kb, VTb, Ob);

    tconv_kernel<<<dim3(64, 64), 256, 0, stream>>>(Wo, WT, 2048, 2048, probe);

    gemm_bias_kernel<<<dim3(32, 16), 256, 0, stream>>>(Ob, WT, boc, d_out, 4096, 2048, 2048, probe, 1.0f);
}

// Round 6
// 460.461 us; speedup vs baseline: 1.3371x; 1.1480x over previous
//
#include <hip/hip_runtime.h>
#include <math.h>

typedef unsigned short u16;
typedef __bf16 bf16_t;
typedef u16 u16x4 __attribute__((ext_vector_type(4)));
typedef u16 u16x8 __attribute__((ext_vector_type(8)));
typedef bf16_t bf16x8 __attribute__((ext_vector_type(8)));
typedef float f32x4 __attribute__((ext_vector_type(4)));

__device__ __forceinline__ float bf2f(u16 v) {
    union { unsigned u; float f; } x; x.u = ((unsigned)v) << 16; return x.f;
}
// Manual RNE f32->bf16 (exact baseline-522 behavior).
__device__ __forceinline__ u16 f2bf(float f) {
    union { float f; unsigned u; } x; x.f = f;
    unsigned u = x.u;
    return (u16)((u + 0x7fffu + ((u >> 16) & 1u)) >> 16);
}

// Async global->LDS DMA, 16B per lane. LDS dest = wave-uniform base + lane*16
// (hardware-defined); global src is per-lane.
__device__ __forceinline__ void gload16(const u16* g, u16* l) {
    __builtin_amdgcn_global_load_lds(
        (const __attribute__((address_space(1))) void*)g,
        (__attribute__((address_space(3))) void*)l,
        16, 0, 0);
}

// ---------------------------------------------------------------------------
// Runtime dtype detector (probe = Wq). bf16: high byte of each u32 is sign/exp
// in [0x38,0x3F]; fp32: uniform mantissa byte. 64-lane majority => exact.
// ---------------------------------------------------------------------------
__device__ __forceinline__ bool is_bf16_input(const unsigned* __restrict__ probe) {
    unsigned w = probe[(threadIdx.x & 63) * 32771 + 7];
    unsigned b7 = (w >> 8) & 0x7f;
    bool hit = (b7 >= 0x38) && (b7 <= 0x3f);
    return __builtin_popcountll(__ballot(hit)) >= 32;
}

__global__ __launch_bounds__(256) void convert_kernel(
    const void* __restrict__ src, u16* __restrict__ dst, int n,
    const unsigned* __restrict__ probe)
{
    bool bf = is_bf16_input(probe);
    int i = (blockIdx.x * 256 + threadIdx.x) * 8;
    if (i >= n) return;
    if (bf) {
        *(u16x8*)&dst[i] = *(const u16x8*)&((const u16*)src)[i];
    } else {
        const float* s = (const float*)src + i;
        u16x8 o;
#pragma unroll
        for (int j = 0; j < 8; j++) o[j] = f2bf(s[j]);
        *(u16x8*)&dst[i] = o;
    }
}

__global__ __launch_bounds__(256) void tconv_kernel(
    const void* __restrict__ in, u16* __restrict__ out, int R, int C,
    const unsigned* __restrict__ probe)
{
    bool bf = is_bf16_input(probe);
    __shared__ u16 t[32][33];
    int x = threadIdx.x & 31, y = threadIdx.x >> 5;
    int bx = blockIdx.x * 32, by = blockIdx.y * 32;
    if (bf) {
        const u16* s = (const u16*)in;
#pragma unroll
        for (int i = 0; i < 32; i += 8)
            t[y + i][x] = s[(size_t)(by + y + i) * C + bx + x];
    } else {
        const float* s = (const float*)in;
#pragma unroll
        for (int i = 0; i < 32; i += 8)
            t[y + i][x] = f2bf(s[(size_t)(by + y + i) * C + bx + x]);
    }
    __syncthreads();
#pragma unroll
    for (int i = 0; i < 32; i += 8)
        out[(size_t)(bx + y + i) * R + by + x] = t[x][y + i];
}

// Transpose with separate input row stride (lets us pull the V columns out of
// the fused QKV output). out[C'][R] from in[R][LD] reading C' columns.
__global__ __launch_bounds__(256) void transpose_kernel(
    const u16* __restrict__ in, u16* __restrict__ out, int R, int LD)
{
    __shared__ u16 t[32][33];
    int x = threadIdx.x & 31, y = threadIdx.x >> 5;
    int bx = blockIdx.x * 32, by = blockIdx.y * 32;
#pragma unroll
    for (int i = 0; i < 32; i += 8)
        t[y + i][x] = in[(size_t)(by + y + i) * LD + bx + x];
    __syncthreads();
#pragma unroll
    for (int i = 0; i < 32; i += 8)
        out[(size_t)(bx + y + i) * R + by + x] = t[x][y + i];
}

// ---------------------------------------------------------------------------
// GEMM: C[M,N] = (A[M,K] @ BT[N,K]^T + bias[N]) * scale
// global_load_lds width=16 staging into linear [128][32] LDS tiles (round-5,
// correctness-proven). Fused-QKV call uses N=3072 -> grid 768 = 3 blocks/CU,
// the occupancy regime the 128^2 structure wants (round-5 post-mortem: the
// old 512/128-block launches were parallelism-starved, not staging-bound).
// ---------------------------------------------------------------------------
__global__ __launch_bounds__(256) void gemm_bias_kernel(
    const u16* __restrict__ A, const u16* __restrict__ BT,
    const u16* __restrict__ bias, void* __restrict__ Cout,
    int M, int N, int K, const unsigned* __restrict__ probe, float scale)
{
    __shared__ __align__(16) u16 As[128 * 32];
    __shared__ __align__(16) u16 Bs[128 * 32];
    const int tid  = threadIdx.x;
    const int lane = tid & 63, wave = tid >> 6;
    const int quad = lane >> 4, li = lane & 15;
    const int bm = blockIdx.x * 128, bn = blockIdx.y * 128;
    const int wm = (wave >> 1) * 64, wn = (wave & 1) * 64;
    const int lrow = lane >> 2;          // 0..15 row within 16-row chunk
    const int lcol = (lane & 3) * 8;     // u16 col offset

    f32x4 acc[4][4] = {};

    for (int k0 = 0; k0 < K; k0 += 32) {
        // async-stage A and B tiles: chunk c = wave*2+j covers rows c*16..+15
#pragma unroll
        for (int j = 0; j < 2; j++) {
            int c = wave * 2 + j;
            int row = c * 16 + lrow;
            gload16(&A [(size_t)(bm + row) * K + k0 + lcol], &As[c * 16 * 32]);
            gload16(&BT[(size_t)(bn + row) * K + k0 + lcol], &Bs[c * 16 * 32]);
        }
        __syncthreads();   // compiler drains vmcnt(0) before barrier: tiles ready
        bf16x8 af[4], bfr[4];
#pragma unroll
        for (int i = 0; i < 4; i++)
            af[i]  = *(const bf16x8*)&As[(wm + i * 16 + li) * 32 + quad * 8];
#pragma unroll
        for (int i = 0; i < 4; i++)
            bfr[i] = *(const bf16x8*)&Bs[(wn + i * 16 + li) * 32 + quad * 8];
#pragma unroll
        for (int mt = 0; mt < 4; mt++)
#pragma unroll
            for (int nt = 0; nt < 4; nt++)
                acc[mt][nt] = __builtin_amdgcn_mfma_f32_16x16x32_bf16(
                    af[mt], bfr[nt], acc[mt][nt], 0, 0, 0);
        __syncthreads();
    }

    bool bf = probe ? is_bf16_input(probe) : true;
    if (bf) {
        u16* C16 = (u16*)Cout;
#pragma unroll
        for (int nt = 0; nt < 4; nt++) {
            int col = bn + wn + nt * 16 + li;
            float bb = bf2f(bias[col]);
#pragma unroll
            for (int mt = 0; mt < 4; mt++)
#pragma unroll
                for (int r = 0; r < 4; r++) {
                    int row = bm + wm + mt * 16 + quad * 4 + r;
                    C16[(size_t)row * N + col] = f2bf((acc[mt][nt][r] + bb) * scale);
                }
        }
    } else {
        float* Cf = (float*)Cout;
#pragma unroll
        for (int nt = 0; nt < 4; nt++) {
            int col = bn + wn + nt * 16 + li;
            float bb = bf2f(bias[col]);
#pragma unroll
            for (int mt = 0; mt < 4; mt++)
#pragma unroll
                for (int r = 0; r < 4; r++) {
                    int row = bm + wm + mt * 16 + quad * 4 + r;
                    Cf[(size_t)row * N + col] = (acc[mt][nt][r] + bb) * scale;
                }
        }
    }
}

// ---------------------------------------------------------------------------
// Flash attention — LITERAL round-0 165 µs body (4 waves/block, 128 q-rows,
// single-buffer K/V LDS staging + register prefetch, 2 barriers, SCALE+__expf
// softmax, per-tile mask, manual f2bf). v4-v8 perturbations all regressed;
// the ONLY change here is the Q/K row stride (3072) because Q and K now live
// in the fused QKV output: Q = QKV col 0, K = QKV col 2048.
// Q:[B*S,3072]  K:[B*S,3072]@+2048  VT:[512, B*S]  O:[B*S, 2048].
// Grid (S/128, H, B).
// ---------------------------------------------------------------------------
__global__ __launch_bounds__(256) void flash_kernel(
    const u16* __restrict__ Q, const u16* __restrict__ Kg,
    const u16* __restrict__ VT, u16* __restrict__ O)
{
    constexpr int S = 2048, D = 2048, DH = 128, QKSTR = 3072;
    constexpr float SCALE = 0.08838834764831845f;  // 1/sqrt(128)
    __shared__ __align__(16) u16 Ks[32 * 136];   // [key][dh]   8704 B
    __shared__ __align__(16) u16 Vt[128 * 40];   // [dh][key]  10240 B
    __shared__ __align__(16) u16 Pw[4][32 * 40]; // [qrow][key] 10240 B

    const int tid  = threadIdx.x;
    const int wave = tid >> 6, lane = tid & 63;
    const int quad = lane >> 4, li = lane & 15;
    const int qt = blockIdx.x, h = blockIdx.y, b = blockIdx.z;
    const int g = h >> 2;
    const int q0w = qt * 128 + wave * 32;        // this wave's first q-row

    const u16* Qb = Q  + (size_t)b * S * QKSTR;
    const u16* Kb = Kg + (size_t)b * S * QKSTR;
    const u16* Vg = VT + (size_t)g * DH * (2 * S) + (size_t)b * S;

    // Q fragments: B-operand, rows q0w + m*16 + li, k = quad*8 (+c*32)
    bf16x8 qf[2][4];
#pragma unroll
    for (int m = 0; m < 2; m++)
#pragma unroll
        for (int c = 0; c < 4; c++)
            qf[m][c] = *(const bf16x8*)&Qb[(size_t)(q0w + m * 16 + li) * QKSTR
                                           + h * DH + c * 32 + quad * 8];

    f32x4 oacc[2][8] = {};
    float mr[2] = { -INFINITY, -INFINITY };
    float lr[2] = { 0.f, 0.f };

    const int kend = qt * 128 + 128;

    // --- register prefetch of tile kc=0 ---
    u16x8 kreg[2], vreg[2];
#pragma unroll
    for (int ch = 0; ch < 2; ch++) {
        int idx = tid + ch * 256;
        kreg[ch] = *(const u16x8*)&Kb[(size_t)(idx >> 4) * QKSTR + g * DH + (idx & 15) * 8];
        vreg[ch] = *(const u16x8*)&Vg[(size_t)(idx >> 2) * (2 * S) + (idx & 3) * 8];
    }

    for (int kc = 0; kc < kend; kc += 32) {
        // commit prefetched tile to LDS
#pragma unroll
        for (int ch = 0; ch < 2; ch++) {
            int idx = tid + ch * 256;
            *(u16x8*)&Ks[(idx >> 4) * 136 + (idx & 15) * 8] = kreg[ch];
            *(u16x8*)&Vt[(idx >> 2) * 40  + (idx & 3) * 8]  = vreg[ch];
        }
        __syncthreads();

        // issue prefetch for next tile (overlaps with compute below)
        int kn = kc + 32;
        if (kn < kend) {
#pragma unroll
            for (int ch = 0; ch < 2; ch++) {
                int idx = tid + ch * 256;
                kreg[ch] = *(const u16x8*)&Kb[(size_t)(kn + (idx >> 4)) * QKSTR
                                              + g * DH + (idx & 15) * 8];
                vreg[ch] = *(const u16x8*)&Vg[(size_t)(idx >> 2) * (2 * S)
                                              + kn + (idx & 3) * 8];
            }
        }

        if (kc <= q0w) {   // causal: tiles with kc > q0w are fully masked
            // S^T = K · Q^T : sacc[m][t], C row = key (quad*4+r), col = qrow (li)
            f32x4 sacc[2][2] = {};
#pragma unroll
            for (int t = 0; t < 2; t++)
#pragma unroll
                for (int c = 0; c < 4; c++) {
                    bf16x8 kf = *(const bf16x8*)&Ks[(t * 16 + li) * 136 + c * 32 + quad * 8];
#pragma unroll
                    for (int m = 0; m < 2; m++)
                        sacc[m][t] = __builtin_amdgcn_mfma_f32_16x16x32_bf16(
                            kf, qf[m][c], sacc[m][t], 0, 0, 0);
                }

            float alpha_b[2][4];
#pragma unroll
            for (int m = 0; m < 2; m++) {
                int row = q0w + m * 16 + li;
                f32x4 s0 = sacc[m][0] * SCALE;
                f32x4 s1 = sacc[m][1] * SCALE;
#pragma unroll
                for (int r = 0; r < 4; r++) {
                    int k0 = kc + quad * 4 + r;
                    if (k0 > row)      s0[r] = -INFINITY;
                    if (k0 + 16 > row) s1[r] = -INFINITY;
                }
                float mx = fmaxf(fmaxf(fmaxf(s0[0], s0[1]), fmaxf(s0[2], s0[3])),
                                 fmaxf(fmaxf(s1[0], s1[1]), fmaxf(s1[2], s1[3])));
                mx = fmaxf(mx, __shfl_xor(mx, 16));
                mx = fmaxf(mx, __shfl_xor(mx, 32));
                float mnew = fmaxf(mr[m], mx);
                float al = __expf(mr[m] - mnew);
                mr[m] = mnew;
                f32x4 p0, p1;
                float ps = 0.f;
#pragma unroll
                for (int r = 0; r < 4; r++) {
                    p0[r] = __expf(s0[r] - mnew);
                    p1[r] = __expf(s1[r] - mnew);
                    ps += p0[r] + p1[r];
                }
                ps += __shfl_xor(ps, 16);
                ps += __shfl_xor(ps, 32);
                lr[m] = lr[m] * al + ps;
                u16x4 c0, c1;
#pragma unroll
                for (int r = 0; r < 4; r++) { c0[r] = f2bf(p0[r]); c1[r] = f2bf(p1[r]); }
                *(u16x4*)&Pw[wave][(m * 16 + li) * 40 + quad * 4]      = c0;
                *(u16x4*)&Pw[wave][(m * 16 + li) * 40 + 16 + quad * 4] = c1;
#pragma unroll
                for (int r = 0; r < 4; r++)
                    alpha_b[m][r] = __shfl(al, quad * 4 + r, 16);
            }

            // rescale O accumulators
#pragma unroll
            for (int m = 0; m < 2; m++)
#pragma unroll
                for (int dt = 0; dt < 8; dt++)
#pragma unroll
                    for (int r = 0; r < 4; r++)
                        oacc[m][dt][r] *= alpha_b[m][r];

            // drain P stores (same wave) before vector re-read
            asm volatile("s_waitcnt lgkmcnt(0)" ::: "memory");
            union { u16x8 u; bf16x8 bv; } pc0, pc1;
            pc0.u = *(const u16x8*)&Pw[wave][(0 * 16 + li) * 40 + quad * 8];
            pc1.u = *(const u16x8*)&Pw[wave][(1 * 16 + li) * 40 + quad * 8];
            bf16x8 pf[2] = { pc0.bv, pc1.bv };

            // O += P · V
#pragma unroll
            for (int dt = 0; dt < 8; dt++) {
                bf16x8 vf = *(const bf16x8*)&Vt[(dt * 16 + li) * 40 + quad * 8];
#pragma unroll
                for (int m = 0; m < 2; m++)
                    oacc[m][dt] = __builtin_amdgcn_mfma_f32_16x16x32_bf16(
                        pf[m], vf, oacc[m][dt], 0, 0, 0);
            }
        }
        __syncthreads();
    }

    u16* Ob = O + (size_t)b * S * D;
#pragma unroll
    for (int m = 0; m < 2; m++) {
#pragma unroll
        for (int r = 0; r < 4; r++) {
            float linv = 1.0f / __shfl(lr[m], quad * 4 + r, 16);
            int row = q0w + m * 16 + quad * 4 + r;
#pragma unroll
            for (int dt = 0; dt < 8; dt++)
                Ob[(size_t)row * D + h * DH + dt * 16 + li] = f2bf(oacc[m][dt][r] * linv);
        }
    }
}

// ---------------------------------------------------------------------------
extern "C" void kernel_launch(void* const* d_in, const int* in_sizes, int n_in,
                              void* d_out, int out_size, void* d_ws, size_t ws_size,
                              hipStream_t stream)
{
    const void* X  = d_in[0];
    const void* Wq = d_in[3];
    const void* bq = d_in[4];
    const void* Wk = d_in[5];
    const void* bk = d_in[6];
    const void* Wv = d_in[7];
    const void* bv = d_in[8];
    const void* Wo = d_in[9];
    const void* bo = d_in[10];
    const unsigned* probe = (const unsigned*)d_in[3];

    u16* ws    = (u16*)d_ws;
    u16* Xc    = ws;                     // [4096][2048]        8388608
    u16* WqkvT = Xc    + 8388608;        // [3072][2048]        6291456 (later reused for WoT)
    u16* bqkv  = WqkvT + 6291456;        // [3072] (bq|bk|bv)
    u16* boc   = bqkv  + 3072;           // [2048]
    u16* QKV   = boc   + 2048;           // [4096][3072]       12582912
    u16* VTb   = QKV   + 12582912;       // [512][4096]         2097152
    u16* Ob    = VTb   + 2097152;        // [4096][2048]        8388608

    convert_kernel<<<4096, 256, 0, stream>>>(X,  Xc,  8388608, probe);
    convert_kernel<<<1,    256, 0, stream>>>(bq, bqkv,        2048, probe);
    convert_kernel<<<1,    256, 0, stream>>>(bk, bqkv + 2048, 512,  probe);
    convert_kernel<<<1,    256, 0, stream>>>(bv, bqkv + 2560, 512,  probe);
    convert_kernel<<<1,    256, 0, stream>>>(bo, boc, 2048, probe);

    // Wqkv^T[3072][2048]: rows 0..2047 = Wq^T, 2048..2559 = Wk^T, 2560..3071 = Wv^T
    tconv_kernel<<<dim3(64, 64), 256, 0, stream>>>(Wq, WqkvT,                  2048, 2048, probe);
    tconv_kernel<<<dim3(16, 64), 256, 0, stream>>>(Wk, WqkvT + 2048 * 2048,    2048, 512,  probe);
    tconv_kernel<<<dim3(16, 64), 256, 0, stream>>>(Wv, WqkvT + 2560 * 2048,    2048, 512,  probe);

    // Fused QKV projection: grid (32,24) = 768 blocks = 3 blocks/CU
    gemm_bias_kernel<<<dim3(32, 24), 256, 0, stream>>>(Xc, WqkvT, bqkv, QKV,
                                                       4096, 3072, 2048, nullptr, 1.0f);

    // V columns (2560..3071) of QKV -> VT[512][4096]
    transpose_kernel<<<dim3(16, 128), 256, 0, stream>>>(QKV + 2560, VTb, 4096, 3072);

    flash_kernel<<<dim3(16, 16, 2), 256, 0, stream>>>(QKV, QKV + 2048, VTb, Ob);

    tconv_kernel<<<dim3(64, 64), 256, 0, stream>>>(Wo, WqkvT, 2048, 2048, probe);

    gemm_bias_kernel<<<dim3(32, 16), 256, 0, stream>>>(Ob, WqkvT, boc, d_out,
                                                       4096, 2048, 2048, probe, 1.0f);
}